// Round 9
// baseline (456.519 us; speedup 1.0000x reference)
//
#include <hip/hip_runtime.h>
#include <hip/hip_fp16.h>
#include <math.h>

#define HH    1024
#define WWID  1024
#define WR    513
#define NIMG  96
#define NGRP  65
#define KSEG  17
#define FEAT  256
#define FIN   144

__device__ __forceinline__ float2 cmul(float2 a, float2 b) {
    return make_float2(a.x * b.x - a.y * b.y, a.x * b.y + a.y * b.x);
}

// exact reference binning (16 compares + sqrt) — used by k_counts
__device__ __forceinline__ int radial_bin(int hf, int k) {
    const float maxr = 0.707106781186547524f;
    float v = (float)(hf < 512 ? hf : hf - 1024) * (1.0f / 1024.0f);
    float u = (float)k * (1.0f / 1024.0f);
    float rad = sqrtf(u * u + v * v);
    int bin = 0;
#pragma unroll
    for (int l = 1; l <= 16; ++l) {
        float lower = (maxr * (float)l) * 0.0625f;
        bin += (rad >= lower) ? 1 : 0;
    }
    return bin;
}

// fast bin with exact boundary adjust (validated r6/r7)
__device__ __forceinline__ int fast_bin(float rad) {
    int c = (int)(rad * 22.62741699796952f);
    if (c > 16) c = 16;
    if (c < 16 && rad >= (0.707106781186547524f * (float)(c + 1)) * 0.0625f) c++;
    else if (rad < (0.707106781186547524f * (float)c) * 0.0625f) c--;
    return c;
}

// ---- register-resident 1024-pt FFT per wave (structure verified r3-r8) --------------
// Steps A+B: input a[BR4[j]] = x[l + 64j]; after call a[r] = V[n1=l][k2=r].
// Returns w1^16 for Step C.
__device__ __forceinline__ float2 wave_fft_AB(float2 a[16], int l) {
    constexpr float TW16C[8] = {1.f, 0.9238795325112867f, 0.7071067811865476f,
                                0.3826834323650898f, 0.f, -0.3826834323650898f,
                                -0.7071067811865476f, -0.9238795325112867f};
    constexpr float TW16S[8] = {0.f, -0.3826834323650898f, -0.7071067811865476f,
                                -0.9238795325112867f, -1.f, -0.9238795325112867f,
                                -0.7071067811865476f, -0.3826834323650898f};
#pragma unroll
    for (int m = 2; m <= 16; m <<= 1) {
        const int half = m >> 1;
        const int tstep = 16 / m;
#pragma unroll
        for (int bse = 0; bse < 16; bse += m) {
#pragma unroll
            for (int jj = 0; jj < 8; ++jj) {
                if (jj < half) {
                    float2 w = make_float2(TW16C[jj * tstep], TW16S[jj * tstep]);
                    float2 tv = cmul(a[bse + half + jj], w);
                    float2 u0 = a[bse + jj];
                    a[bse + jj]        = make_float2(u0.x + tv.x, u0.y + tv.y);
                    a[bse + half + jj] = make_float2(u0.x - tv.x, u0.y - tv.y);
                }
            }
        }
    }
    // Step B: HW-trig base twiddle (|ang| <= 0.39 rad, err ~1e-6), two-level products
    float ang = (float)l * (-6.28318530717958647692f / 1024.0f);
    float2 w1 = make_float2(__cosf(ang), __sinf(ang));
    float2 w2 = cmul(w1, w1);
    float2 w3 = cmul(w2, w1);
    float2 w4 = cmul(w2, w2);
    float2 w8 = cmul(w4, w4);
    float2 w12 = cmul(w8, w4);
    a[1] = cmul(a[1], w1);
    a[2] = cmul(a[2], w2);
    a[3] = cmul(a[3], w3);
#pragma unroll
    for (int r = 4; r < 16; ++r) {
        float2 hi = (r >> 2) == 1 ? w4 : ((r >> 2) == 2 ? w8 : w12);
        float2 p = cmul(a[r], hi);
        int lo = r & 3;
        if (lo == 1) p = cmul(p, w1);
        else if (lo == 2) p = cmul(p, w2);
        else if (lo == 3) p = cmul(p, w3);
        a[r] = p;
    }
    return cmul(w8, w8); // w1^16
}

// Step C (fp32, used by colfft): fma-form butterfly + unconditional twiddle.
// Output: lane p, reg r <-> X[16*bitrev6(p) + r].
__device__ __forceinline__ void wave_fft_C(float2 a[16], int l, float2 u) {
#pragma unroll
    for (int half = 32; half >= 1; half >>= 1) {
        const bool up = (l & half) != 0;
        const float sgn = up ? -1.0f : 1.0f;
        const float twx = up ? -u.x : 1.0f;   // down lanes: identity twiddle
        const float twy = up ? -u.y : 0.0f;
#pragma unroll
        for (int r = 0; r < 16; ++r) {
            float ox = __shfl_xor(a[r].x, half);
            float oy = __shfl_xor(a[r].y, half);
            float sx = fmaf(sgn, a[r].x, ox);   // down: a+o, up: o-a
            float sy = fmaf(sgn, a[r].y, oy);
            a[r].x = fmaf(sx, twx, -(sy * twy));
            a[r].y = fmaf(sx, twy, sy * twx);
        }
        if (half > 1) u = cmul(u, u);
    }
}

// Step C packed fp16 (used by rowfft — output is fp16 interm anyway).
// Each complex value = one __half2 VGPR; butterfly = 1 shuffle + 1 pk_fma;
// twiddle cmul = alignbit-swap + pk_mul + pk_fma.  5 issues/reg/stage vs 8.
__device__ __forceinline__ void wave_fft_C_h2(__half2 h[16], int l, float2 u) {
#pragma unroll
    for (int half = 32; half >= 1; half >>= 1) {
        const bool up = (l & half) != 0;
        const float sg = up ? -1.0f : 1.0f;
        const float twx = up ? -u.x : 1.0f;   // down lanes: identity twiddle
        const float twy = up ? -u.y : 0.0f;
        const __half2 sgn2 = __floats2half2_rn(sg, sg);
        const __half2 twxx = __floats2half2_rn(twx, twx);
        const __half2 twyy = __floats2half2_rn(-twy, twy);
#pragma unroll
        for (int r = 0; r < 16; ++r) {
            unsigned au;
            __builtin_memcpy(&au, &h[r], 4);
            unsigned ou = (unsigned)__shfl_xor((int)au, half);
            __half2 o;
            __builtin_memcpy(&o, &ou, 4);
            __half2 s = __hfma2(h[r], sgn2, o);      // down: a+o, up: o-a
            unsigned su;
            __builtin_memcpy(&su, &s, 4);
            unsigned swu = (su >> 16) | (su << 16);  // (sy, sx)
            __half2 sw;
            __builtin_memcpy(&sw, &swu, 4);
            // (sx*twx - sy*twy, sy*twx + sx*twy)
            h[r] = __hfma2(sw, twyy, __hmul2(s, twxx));
        }
        if (half > 1) u = cmul(u, u);
    }
}

static __device__ __constant__ int BR4[16] = {0,8,4,12,2,10,6,14,1,9,5,13,3,11,7,15};

// ---------------- Kernel 1: row FFTs; PACKED spectrum, fp16 Step C -------------------
// Pairing: Z[q] = row q + i*row (q+512), q = 0..511.
// interm layout: [k][perm(q)] with perm(q) = (q&63)*8 + (q>>6)  (1024 x 512 half2).
// Block = 1024 thr = 16 waves; wave w owns q with perm(q) = blk*16 + w.
__global__ __launch_bounds__(1024) void k_rowfft(const float* __restrict__ x,
                                                 __half2* __restrict__ interm,
                                                 int img0) {
    __shared__ __half2 tile[1024][17]; // [k][slot], XOR swizzle on slot
    const int t = threadIdx.x;
    const int w = t >> 6;      // 0..15
    const int l = t & 63;
    const int blk = blockIdx.x;           // 0..31
    const int iy = blockIdx.y;
    const int img = img0 + iy;
    const int hA = ((w & 7) << 6) + 2 * blk + (w >> 3);
    const int hB = hA + 512;

    const float* r1 = x + ((size_t)img * HH + hA) * WWID;
    const float* r2 = x + ((size_t)img * HH + hB) * WWID;
    float2 a[16];
#pragma unroll
    for (int j = 0; j < 16; ++j) {
        int i = l + 64 * j;
        a[BR4[j]] = make_float2(r1[i], r2[i]);
    }

    float2 u16 = wave_fft_AB(a, l);

    // convert to packed fp16 (this rounding was previously done at tile write)
    __half2 h[16];
#pragma unroll
    for (int r = 0; r < 16; ++r)
        h[r] = __floats2half2_rn(a[r].x, a[r].y);

    wave_fft_C_h2(h, l, u16);

    // reg r at lane l holds Z[k], k = 16*bitrev6(l)+r — store packed, no unpack
    const int b = (int)(__brev((unsigned)l) >> 26);
#pragma unroll
    for (int r = 0; r < 16; ++r) {
        int k = 16 * b + r;
        tile[k][w ^ (b & 15)] = h[r];
    }
    __syncthreads();

    // coalesced write-out: (k, s) -> k*512 + blk*16 + s  (64B runs per k)
    __half2* gout = interm + (size_t)iy * 1024 * 512 + blk * 16;
#pragma unroll
    for (int it = 0; it < 16; ++it) {
        int idx = t + it * 1024;
        int k = idx >> 4;
        int s = idx & 15;
        gout[(size_t)k * 512 + s] = tile[k][s ^ ((k >> 4) & 15)];
    }
}

// ------------- Kernel 2: column FFTs — unpack-on-load from packed Z ------------------
__global__ __launch_bounds__(512) void k_colfft(const __half2* __restrict__ interm,
                                                float* __restrict__ partials,
                                                int img0) {
    __shared__ float wsum[8][KSEG][2];
    __shared__ unsigned wmax[8][KSEG];
    const int t = threadIdx.x;
    const int g = blockIdx.x;
    const int iy = blockIdx.y;
    const int img = img0 + iy;
    const int wv = t >> 6;
    const int l = t & 63;
    const int k = g * 8 + wv;

    for (int i = t; i < 8 * KSEG; i += 512) {
        int w = i / KSEG, bb = i - w * KSEG;
        wsum[w][bb][0] = 0.f; wsum[w][bb][1] = 0.f; wmax[w][bb] = 0u;
    }
    __syncthreads();

    if (k <= 512) {   // wave-uniform
        const int kn = (1024 - k) & 1023;
        const uint4* ps = (const uint4*)(interm + ((size_t)iy * 1024 + k) * 512 + l * 8);
        const uint4* pn = (const uint4*)(interm + ((size_t)iy * 1024 + kn) * 512 + l * 8);
        union QU { uint4 q[2]; __half2 h[8]; } us, un;
        us.q[0] = ps[0]; us.q[1] = ps[1];
        un.q[0] = pn[0]; un.q[1] = pn[1];

        float2 a[16];
#pragma unroll
        for (int m = 0; m < 8; ++m) {
            float2 zs = __half22float2(us.h[m]);
            float2 zn = __half22float2(un.h[m]);
            a[BR4[m]]     = make_float2(0.5f * (zs.x + zn.x), 0.5f * (zs.y - zn.y));
            a[BR4[m + 8]] = make_float2(0.5f * (zs.y + zn.y), 0.5f * (zn.x - zs.x));
        }

        float2 u16 = wave_fft_AB(a, l);
        wave_fft_C(a, l, u16);

        // stats: lane's 16 rows contiguous [16b, 16b+15] -> at most 2 bins (verified r3)
        const int b = (int)(__brev((unsigned)l) >> 26);
        const int h0 = 16 * b;
        // h0 is a multiple of 16 -> the 16-row run never straddles the 512 boundary
        const float vbase = (float)(h0 < 512 ? h0 : h0 - 1024);
        const float uf = (float)k * (1.0f / 1024.0f);
        const float uu = uf * uf;
        float vf0 = vbase * (1.0f / 1024.0f);
        float vfF = (vbase + 15.0f) * (1.0f / 1024.0f);
        int binF = fast_bin(sqrtf(fmaf(vf0, vf0, uu)));
        int binL = fast_bin(sqrtf(fmaf(vfF, vfF, uu)));
        const int bHi = (binF > binL) ? binF : binL;
        const float Lmid = (0.707106781186547524f * (float)bHi) * 0.0625f;
        const float Lmid2 = Lmid * Lmid;

        // accumulate UNSCALED sqrt(p2)/p2; apply 1/1024 scalings once at the end
        float sA1 = 0.f, sA2 = 0.f, mA = 0.f;
        float sB1 = 0.f, sB2 = 0.f, mB = 0.f;
#pragma unroll
        for (int r = 0; r < 16; ++r) {
            float vf = (vbase + (float)r) * (1.0f / 1024.0f);
            float s = fmaf(vf, vf, uu);                    // exact rad^2
            float2 z = a[r];
            float p2 = fmaf(z.x, z.x, z.y * z.y);
            float m = sqrtf(p2);
            bool c = (s >= Lmid2);                         // bin == bHi
            sA1 += c ? m : 0.f;
            sA2 += c ? p2 : 0.f;
            mA = fmaxf(mA, c ? m : 0.f);
            sB1 += c ? 0.f : m;
            sB2 += c ? 0.f : p2;
            mB = fmaxf(mB, c ? 0.f : m);
        }
        const float c1 = 1.0f / 1024.0f;
        const float c2 = 1.0f / 1048576.0f;

        atomicAdd(&wsum[wv][bHi][0], sA1 * c1);
        atomicAdd(&wsum[wv][bHi][1], sA2 * c2);
        atomicMax(&wmax[wv][bHi], __float_as_uint(mA * c1));
        if (bHi > 0) {
            atomicAdd(&wsum[wv][bHi - 1][0], sB1 * c1);
            atomicAdd(&wsum[wv][bHi - 1][1], sB2 * c2);
            atomicMax(&wmax[wv][bHi - 1], __float_as_uint(mB * c1));
        }
    }
    __syncthreads();

    if (t < KSEG) {
        float aS = 0.f, bS = 0.f, cM = 0.f;
#pragma unroll
        for (int w = 0; w < 8; ++w) {
            aS += wsum[w][t][0];
            bS += wsum[w][t][1];
            cM = fmaxf(cM, __uint_as_float(wmax[w][t]));
        }
        float* dstp = partials + ((size_t)img * NGRP + g) * (KSEG * 3) + t * 3;
        dstp[0] = aS; dstp[1] = bS; dstp[2] = cM;
    }
}

// ---------------- counts (exact reference binning, deterministic) --------------------
__global__ __launch_bounds__(256) void k_counts(unsigned* __restrict__ counts) {
    int cnt[KSEG];
#pragma unroll
    for (int l = 0; l < KSEG; ++l) cnt[l] = 0;
    const int total = HH * WR;
    for (int idx = blockIdx.x * 256 + threadIdx.x; idx < total; idx += gridDim.x * 256) {
        int h = idx / WR;
        int k = idx - h * WR;
        int bin = radial_bin(h, k);
#pragma unroll
        for (int l = 0; l < KSEG; ++l) cnt[l] += (bin == l) ? 1 : 0;
    }
    const int lane = threadIdx.x & 63;
#pragma unroll
    for (int l = 0; l < KSEG; ++l) {
        int c = cnt[l];
        for (int off = 32; off > 0; off >>= 1) c += __shfl_xor(c, off);
        if (lane == 0 && c > 0) atomicAdd(&counts[l], (unsigned)c);
    }
}

// ---------------- Kernel 3: finalize stats + MLP + LayerNorm -------------------------
__global__ __launch_bounds__(256) void k_mlp(const float* __restrict__ partials,
                                             const unsigned* __restrict__ counts,
                                             const float* __restrict__ W1,
                                             const float* __restrict__ b1,
                                             const float* __restrict__ W2,
                                             const float* __restrict__ b2,
                                             const float* __restrict__ gamma,
                                             const float* __restrict__ beta,
                                             float* __restrict__ out) {
    __shared__ float feat[FIN];
    __shared__ float h1s[FEAT];
    __shared__ float red[FEAT];
    const int b = blockIdx.x;
    const int t = threadIdx.x;
    if (t < 48) {
        int c = t / 16;
        int bin = t % 16;
        const float* p = partials + ((size_t)(b * 3 + c) * NGRP) * (KSEG * 3) + bin * 3;
        float s1 = 0.f, s2 = 0.f, mxv = 0.f;
        for (int gg = 0; gg < NGRP; ++gg) {
            s1 += p[gg * (KSEG * 3) + 0];
            s2 += p[gg * (KSEG * 3) + 1];
            mxv = fmaxf(mxv, p[gg * (KSEG * 3) + 2]);
        }
        float cntf = (float)counts[bin];
        float denom = cntf + 1e-8f;
        float mean = s1 / denom;
        float var = (s2 - 2.0f * mean * s1 + cntf * mean * mean) / denom;
        var = fmaxf(var, 0.0f);
        float sd = sqrtf(var);
        mxv = fmaxf(mxv, 0.0f);
        feat[bin * 9 + 0 + c] = mean;
        feat[bin * 9 + 3 + c] = mxv;
        feat[bin * 9 + 6 + c] = sd;
    }
    __syncthreads();

    float acc = b1[t];
    for (int i = 0; i < FIN; ++i) acc += feat[i] * W1[i * FEAT + t];
    acc = (acc >= 0.0f) ? acc : 0.2f * acc;
    h1s[t] = acc;
    __syncthreads();

    float acc2 = b2[t];
    for (int i = 0; i < FEAT; ++i) acc2 += h1s[i] * W2[i * FEAT + t];

    red[t] = acc2;
    __syncthreads();
    for (int off = 128; off > 0; off >>= 1) {
        if (t < off) red[t] += red[t + off];
        __syncthreads();
    }
    float mu = red[0] * (1.0f / 256.0f);
    __syncthreads();
    float dvt = acc2 - mu;
    red[t] = dvt * dvt;
    __syncthreads();
    for (int off = 128; off > 0; off >>= 1) {
        if (t < off) red[t] += red[t + off];
        __syncthreads();
    }
    float va = red[0] * (1.0f / 256.0f);
    out[(size_t)b * FEAT + t] = dvt / sqrtf(va + 1e-5f) * gamma[t] + beta[t];
}

// --------------------------------------------------------------------------------------
extern "C" void kernel_launch(void* const* d_in, const int* in_sizes, int n_in,
                              void* d_out, int out_size, void* d_ws, size_t ws_size,
                              hipStream_t stream) {
    const float* x     = (const float*)d_in[0];
    const float* W1    = (const float*)d_in[1];
    const float* b1    = (const float*)d_in[2];
    const float* W2    = (const float*)d_in[3];
    const float* b2    = (const float*)d_in[4];
    const float* gamma = (const float*)d_in[5];
    const float* beta  = (const float*)d_in[6];
    float* out = (float*)d_out;

    char* ws = (char*)d_ws;
    unsigned* counts = (unsigned*)ws;
    float* partials = (float*)(ws + 256);
    const size_t partialsBytes = (size_t)NIMG * NGRP * KSEG * 3 * sizeof(float);
    const size_t intermOff = (256 + partialsBytes + 255) & ~(size_t)255;
    __half2* interm = (__half2*)(ws + intermOff);
    const size_t perImg = (size_t)1024 * 512 * sizeof(__half2);

    long long avail = (long long)ws_size - (long long)intermOff;
    int chunk = (avail > 0) ? (int)(avail / (long long)perImg) : 0;
    if (chunk > NIMG) chunk = NIMG;
    if (chunk < 1) chunk = 1;

    hipMemsetAsync(counts, 0, KSEG * sizeof(unsigned), stream);
    k_counts<<<dim3(128), dim3(256), 0, stream>>>(counts);

    for (int img0 = 0; img0 < NIMG; img0 += chunk) {
        int n = NIMG - img0;
        if (n > chunk) n = chunk;
        k_rowfft<<<dim3(32, n), dim3(1024), 0, stream>>>(x, interm, img0);
        k_colfft<<<dim3(NGRP, n), dim3(512), 0, stream>>>(interm, partials, img0);
    }

    k_mlp<<<dim3(32), dim3(256), 0, stream>>>(partials, counts, W1, b1, W2, b2,
                                              gamma, beta, out);
}

// Round 10
// 432.149 us; speedup vs baseline: 1.0564x; 1.0564x over previous
//
#include <hip/hip_runtime.h>
#include <hip/hip_fp16.h>
#include <math.h>

#define HH    1024
#define WWID  1024
#define WR    513
#define NIMG  96
#define NGRP  65
#define KSEG  17
#define FEAT  256
#define FIN   144

__device__ __forceinline__ float2 cmul(float2 a, float2 b) {
    return make_float2(a.x * b.x - a.y * b.y, a.x * b.y + a.y * b.x);
}

// exact reference binning (16 compares + sqrt) — used by k_counts
__device__ __forceinline__ int radial_bin(int hf, int k) {
    const float maxr = 0.707106781186547524f;
    float v = (float)(hf < 512 ? hf : hf - 1024) * (1.0f / 1024.0f);
    float u = (float)k * (1.0f / 1024.0f);
    float rad = sqrtf(u * u + v * v);
    int bin = 0;
#pragma unroll
    for (int l = 1; l <= 16; ++l) {
        float lower = (maxr * (float)l) * 0.0625f;
        bin += (rad >= lower) ? 1 : 0;
    }
    return bin;
}

// fast bin with exact boundary adjust (validated r6/r7)
__device__ __forceinline__ int fast_bin(float rad) {
    int c = (int)(rad * 22.62741699796952f);
    if (c > 16) c = 16;
    if (c < 16 && rad >= (0.707106781186547524f * (float)(c + 1)) * 0.0625f) c++;
    else if (rad < (0.707106781186547524f * (float)c) * 0.0625f) c--;
    return c;
}

__device__ constexpr int BR4[16] = {0,8,4,12,2,10,6,14,1,9,5,13,3,11,7,15};

// ---- cross-lane exchange: guaranteed single-issue ds ops -----------------------------
template<int HALF>
__device__ __forceinline__ float sxl(float v, int addr32) {
    if constexpr (HALF == 32)
        return __int_as_float(__builtin_amdgcn_ds_bpermute(addr32, __float_as_int(v)));
    else
        return __int_as_float(__builtin_amdgcn_ds_swizzle(__float_as_int(v),
                                                          (HALF << 10) | 0x1F));
}

template<int HALF>
__device__ __forceinline__ void fftC_stage(float2 a[16], int l, float2 u, int addr32) {
    const bool up = (l & HALF) != 0;
    const float sgn = up ? -1.0f : 1.0f;
    const float twx = up ? -u.x : 1.0f;   // down lanes: identity twiddle
    const float twy = up ? -u.y : 0.0f;
#pragma unroll
    for (int r = 0; r < 16; ++r) {
        float ox = sxl<HALF>(a[r].x, addr32);
        float oy = sxl<HALF>(a[r].y, addr32);
        float sx = fmaf(sgn, a[r].x, ox);   // down: a+o, up: o-a
        float sy = fmaf(sgn, a[r].y, oy);
        a[r].x = fmaf(sx, twx, -(sy * twy));
        a[r].y = fmaf(sx, twy, sy * twx);
    }
}

// 64-pt DIF across lanes (per register, independently). natural in -> bitrev out.
// u must be W_64^l.  (verified structure r3-r8)
__device__ __forceinline__ void wave_fft_C(float2 a[16], int l, float2 u) {
    const int addr32 = ((l ^ 32) << 2);
    fftC_stage<32>(a, l, u, addr32); u = cmul(u, u);
    fftC_stage<16>(a, l, u, addr32); u = cmul(u, u);
    fftC_stage<8>(a, l, u, addr32);  u = cmul(u, u);
    fftC_stage<4>(a, l, u, addr32);  u = cmul(u, u);
    fftC_stage<2>(a, l, u, addr32);  u = cmul(u, u);
    fftC_stage<1>(a, l, u, addr32);
}

// 16-pt DIT over registers: input reg r = element BR4[r] (bitrev order), natural out.
__device__ __forceinline__ void fft16_regs(float2 a[16]) {
    constexpr float TW16C[8] = {1.f, 0.9238795325112867f, 0.7071067811865476f,
                                0.3826834323650898f, 0.f, -0.3826834323650898f,
                                -0.7071067811865476f, -0.9238795325112867f};
    constexpr float TW16S[8] = {0.f, -0.3826834323650898f, -0.7071067811865476f,
                                -0.9238795325112867f, -1.f, -0.9238795325112867f,
                                -0.7071067811865476f, -0.3826834323650898f};
#pragma unroll
    for (int m = 2; m <= 16; m <<= 1) {
        const int half = m >> 1;
        const int tstep = 16 / m;
#pragma unroll
        for (int bse = 0; bse < 16; bse += m) {
#pragma unroll
            for (int jj = 0; jj < 8; ++jj) {
                if (jj < half) {
                    float2 w = make_float2(TW16C[jj * tstep], TW16S[jj * tstep]);
                    float2 tv = cmul(a[bse + half + jj], w);
                    float2 u0 = a[bse + jj];
                    a[bse + jj]        = make_float2(u0.x + tv.x, u0.y + tv.y);
                    a[bse + half + jj] = make_float2(u0.x - tv.x, u0.y - tv.y);
                }
            }
        }
    }
}

// twiddle a[r] *= wb^{e_r}; wb from __cosf/__sinf (|ang|<=0.39 rad), two-level chain.
template<bool PERM>  // e_r = PERM ? BR4[r] : r
__device__ __forceinline__ void twiddle_regs(float2 a[16], float ang, float2* w16out) {
    float2 w1 = make_float2(__cosf(ang), __sinf(ang));
    float2 w2 = cmul(w1, w1);
    float2 w3 = cmul(w2, w1);
    float2 w4 = cmul(w2, w2);
    float2 w8 = cmul(w4, w4);
    float2 w12 = cmul(w8, w4);
#pragma unroll
    for (int r = 1; r < 16; ++r) {
        const int e = PERM ? BR4[r] : r;
        float2 p = a[r];
        const int hi = e >> 2, lo = e & 3;
        if (hi == 1) p = cmul(p, w4);
        else if (hi == 2) p = cmul(p, w8);
        else if (hi == 3) p = cmul(p, w12);
        if (lo == 1) p = cmul(p, w1);
        else if (lo == 2) p = cmul(p, w2);
        else if (lo == 3) p = cmul(p, w3);
        a[r] = p;
    }
    if (w16out) *w16out = cmul(w8, w8);
}

// ---------------- Kernel 1: row FFTs — contiguous loads, C-first factorization -------
// n = 16*l + j.  Step 1: 64-pt lane FFT per reg; Step 2: twiddle W_1024^{BR4[r]*b},
// b = bitrev6(l); Step 3: 16-pt reg FFT.  Z[k], k = b + 64r.
// Pairing: Z_q = row hA + i*row hB, hA = (w&7)*64 + 2*blk + (w>>3), hB = hA+512.
// interm layout: [k][blk*16 + w]  (k-major, 1024 x 512 half2) — same as r8.
__global__ __launch_bounds__(1024) void k_rowfft(const float* __restrict__ x,
                                                 __half2* __restrict__ interm,
                                                 int img0) {
    __shared__ __half2 tile[1024][17]; // [k][slot], +1 pad (2-way banks by construction)
    const int t = threadIdx.x;
    const int w = t >> 6;      // 0..15
    const int l = t & 63;
    const int blk = blockIdx.x;           // 0..31
    const int iy = blockIdx.y;
    const int img = img0 + iy;
    const int hA = ((w & 7) << 6) + 2 * blk + (w >> 3);
    const int hB = hA + 512;

    const float4* r1 = (const float4*)(x + ((size_t)img * HH + hA) * WWID) + 4 * l;
    const float4* r2 = (const float4*)(x + ((size_t)img * HH + hB) * WWID) + 4 * l;
    float4 f1[4], f2[4];
#pragma unroll
    for (int c = 0; c < 4; ++c) { f1[c] = r1[c]; f2[c] = r2[c]; }

    float2 a[16];
#pragma unroll
    for (int j = 0; j < 16; ++j) {
        float v1 = ((const float*)f1)[j];   // unrolled -> static indexing
        float v2 = ((const float*)f2)[j];
        a[BR4[j]] = make_float2(v1, v2);
    }

    // Step 1: 64-pt lane FFT on each register (natural lane in, bitrev lane out)
    float angL = (float)l * (-6.28318530717958647692f / 64.0f);
    wave_fft_C(a, l, make_float2(__cosf(angL), __sinf(angL)));

    const int b = (int)(__brev((unsigned)l) >> 26);   // k1 = bitrev6(l)

    // Step 2: twiddle reg r by W_1024^{BR4[r]*b}
    float angB = (float)b * (-6.28318530717958647692f / 1024.0f);
    twiddle_regs<true>(a, angB, nullptr);

    // Step 3: 16-pt register FFT (bitrev reg in, natural k2 out)
    fft16_regs(a);

    // Z[k], k = b + 64r — packed store (unpack deferred to colfft)
#pragma unroll
    for (int r = 0; r < 16; ++r)
        tile[b + 64 * r][w] = __floats2half2_rn(a[r].x, a[r].y);
    __syncthreads();

    // coalesced write-out: (k, s) -> k*512 + blk*16 + s  (64B runs per k)
    __half2* gout = interm + (size_t)iy * 1024 * 512 + blk * 16;
#pragma unroll
    for (int it = 0; it < 16; ++it) {
        int idx = t + it * 1024;
        int k = idx >> 4;
        int s = idx & 15;
        gout[(size_t)k * 512 + s] = tile[k][s];
    }
}

// ------------- Kernel 2: column FFTs — unpack-on-load, 8x-spread LDS atomics ---------
__global__ __launch_bounds__(512) void k_colfft(const __half2* __restrict__ interm,
                                                float* __restrict__ partials,
                                                int img0) {
    __shared__ float wsum[8][KSEG][8][2];      // [wave][bin][slot][s1,s2]
    __shared__ unsigned wmax[8][KSEG][8];
    const int t = threadIdx.x;
    const int g = blockIdx.x;
    const int iy = blockIdx.y;
    const int img = img0 + iy;
    const int wv = t >> 6;
    const int l = t & 63;
    const int k = g * 8 + wv;
    const int slot = l & 7;

    for (int i = t; i < 8 * KSEG * 8; i += 512) {
        int w = i >> 7;            // /(KSEG*8) ~ careful: 17*8=136, not pow2
        int rem = i - w * 136;
        if (w < 8 && rem < 136) {
            int bb = rem >> 3, sl = rem & 7;
            wsum[w][bb][sl][0] = 0.f;
            wsum[w][bb][sl][1] = 0.f;
            wmax[w][bb][sl] = 0u;
        }
    }
    // the i>>7 guess above can miss entries; do an exact second sweep for safety
    for (int i = t; i < 8 * 136; i += 512) {
        int w = i / 136;
        int rem = i - w * 136;
        int bb = rem >> 3, sl = rem & 7;
        wsum[w][bb][sl][0] = 0.f;
        wsum[w][bb][sl][1] = 0.f;
        wmax[w][bb][sl] = 0u;
    }
    __syncthreads();

    if (k <= 512) {   // wave-uniform
        const int kn = (1024 - k) & 1023;
        const uint4* ps = (const uint4*)(interm + ((size_t)iy * 1024 + k) * 512 + l * 8);
        const uint4* pn = (const uint4*)(interm + ((size_t)iy * 1024 + kn) * 512 + l * 8);
        union QU { uint4 q[2]; __half2 h[8]; } us, un;
        us.q[0] = ps[0]; us.q[1] = ps[1];
        un.q[0] = pn[0]; un.q[1] = pn[1];

        float2 a[16];
#pragma unroll
        for (int m = 0; m < 8; ++m) {
            float2 zs = __half22float2(us.h[m]);
            float2 zn = __half22float2(un.h[m]);
            a[BR4[m]]     = make_float2(0.5f * (zs.x + zn.x), 0.5f * (zs.y - zn.y));
            a[BR4[m + 8]] = make_float2(0.5f * (zs.y + zn.y), 0.5f * (zn.x - zs.x));
        }

        // Steps A+B+C (r8 order): 16-pt reg FFT, twiddle W_1024^{l*r}, 64-pt lane FFT
        fft16_regs(a);
        float2 u16;
        float angB = (float)l * (-6.28318530717958647692f / 1024.0f);
        twiddle_regs<false>(a, angB, &u16);
        wave_fft_C(a, l, u16);

        // stats: lane's 16 rows contiguous [16b, 16b+15] -> at most 2 bins (verified r3)
        const int b = (int)(__brev((unsigned)l) >> 26);
        const int h0 = 16 * b;
        const float vbase = (float)(h0 < 512 ? h0 : h0 - 1024);
        const float uf = (float)k * (1.0f / 1024.0f);
        const float uu = uf * uf;
        float vf0 = vbase * (1.0f / 1024.0f);
        float vfF = (vbase + 15.0f) * (1.0f / 1024.0f);
        int binF = fast_bin(sqrtf(fmaf(vf0, vf0, uu)));
        int binL = fast_bin(sqrtf(fmaf(vfF, vfF, uu)));
        const int bHi = (binF > binL) ? binF : binL;
        const float Lmid = (0.707106781186547524f * (float)bHi) * 0.0625f;
        const float Lmid2 = Lmid * Lmid;

        float sA1 = 0.f, sA2 = 0.f, mA = 0.f;
        float sB1 = 0.f, sB2 = 0.f, mB = 0.f;
#pragma unroll
        for (int r = 0; r < 16; ++r) {
            float vf = (vbase + (float)r) * (1.0f / 1024.0f);
            float s = fmaf(vf, vf, uu);                    // exact rad^2
            float2 z = a[r];
            float p2 = fmaf(z.x, z.x, z.y * z.y);
            float m = sqrtf(p2);
            bool c = (s >= Lmid2);                         // bin == bHi
            sA1 += c ? m : 0.f;
            sA2 += c ? p2 : 0.f;
            mA = fmaxf(mA, c ? m : 0.f);
            sB1 += c ? 0.f : m;
            sB2 += c ? 0.f : p2;
            mB = fmaxf(mB, c ? 0.f : m);
        }
        const float c1 = 1.0f / 1024.0f;
        const float c2 = 1.0f / 1048576.0f;

        // 8x-spread atomics: 8 lanes/address max (was 64), slots in distinct banks
        atomicAdd(&wsum[wv][bHi][slot][0], sA1 * c1);
        atomicAdd(&wsum[wv][bHi][slot][1], sA2 * c2);
        atomicMax(&wmax[wv][bHi][slot], __float_as_uint(mA * c1));
        if (bHi > 0) {
            atomicAdd(&wsum[wv][bHi - 1][slot][0], sB1 * c1);
            atomicAdd(&wsum[wv][bHi - 1][slot][1], sB2 * c2);
            atomicMax(&wmax[wv][bHi - 1][slot], __float_as_uint(mB * c1));
        }
    }
    __syncthreads();

    if (t < KSEG) {
        float aS = 0.f, bS = 0.f, cM = 0.f;
#pragma unroll
        for (int w = 0; w < 8; ++w)
#pragma unroll
            for (int sl = 0; sl < 8; ++sl) {
                aS += wsum[w][t][sl][0];
                bS += wsum[w][t][sl][1];
                cM = fmaxf(cM, __uint_as_float(wmax[w][t][sl]));
            }
        float* dstp = partials + ((size_t)img * NGRP + g) * (KSEG * 3) + t * 3;
        dstp[0] = aS; dstp[1] = bS; dstp[2] = cM;
    }
}

// ---------------- counts (exact reference binning, deterministic) --------------------
__global__ __launch_bounds__(256) void k_counts(unsigned* __restrict__ counts) {
    int cnt[KSEG];
#pragma unroll
    for (int l = 0; l < KSEG; ++l) cnt[l] = 0;
    const int total = HH * WR;
    for (int idx = blockIdx.x * 256 + threadIdx.x; idx < total; idx += gridDim.x * 256) {
        int h = idx / WR;
        int k = idx - h * WR;
        int bin = radial_bin(h, k);
#pragma unroll
        for (int l = 0; l < KSEG; ++l) cnt[l] += (bin == l) ? 1 : 0;
    }
    const int lane = threadIdx.x & 63;
#pragma unroll
    for (int l = 0; l < KSEG; ++l) {
        int c = cnt[l];
        for (int off = 32; off > 0; off >>= 1) c += __shfl_xor(c, off);
        if (lane == 0 && c > 0) atomicAdd(&counts[l], (unsigned)c);
    }
}

// ---------------- Kernel 3: finalize stats + MLP + LayerNorm -------------------------
__global__ __launch_bounds__(256) void k_mlp(const float* __restrict__ partials,
                                             const unsigned* __restrict__ counts,
                                             const float* __restrict__ W1,
                                             const float* __restrict__ b1,
                                             const float* __restrict__ W2,
                                             const float* __restrict__ b2,
                                             const float* __restrict__ gamma,
                                             const float* __restrict__ beta,
                                             float* __restrict__ out) {
    __shared__ float feat[FIN];
    __shared__ float h1s[FEAT];
    __shared__ float red[FEAT];
    const int b = blockIdx.x;
    const int t = threadIdx.x;
    if (t < 48) {
        int c = t / 16;
        int bin = t % 16;
        const float* p = partials + ((size_t)(b * 3 + c) * NGRP) * (KSEG * 3) + bin * 3;
        float s1 = 0.f, s2 = 0.f, mxv = 0.f;
        for (int gg = 0; gg < NGRP; ++gg) {
            s1 += p[gg * (KSEG * 3) + 0];
            s2 += p[gg * (KSEG * 3) + 1];
            mxv = fmaxf(mxv, p[gg * (KSEG * 3) + 2]);
        }
        float cntf = (float)counts[bin];
        float denom = cntf + 1e-8f;
        float mean = s1 / denom;
        float var = (s2 - 2.0f * mean * s1 + cntf * mean * mean) / denom;
        var = fmaxf(var, 0.0f);
        float sd = sqrtf(var);
        mxv = fmaxf(mxv, 0.0f);
        feat[bin * 9 + 0 + c] = mean;
        feat[bin * 9 + 3 + c] = mxv;
        feat[bin * 9 + 6 + c] = sd;
    }
    __syncthreads();

    float acc = b1[t];
    for (int i = 0; i < FIN; ++i) acc += feat[i] * W1[i * FEAT + t];
    acc = (acc >= 0.0f) ? acc : 0.2f * acc;
    h1s[t] = acc;
    __syncthreads();

    float acc2 = b2[t];
    for (int i = 0; i < FEAT; ++i) acc2 += h1s[i] * W2[i * FEAT + t];

    red[t] = acc2;
    __syncthreads();
    for (int off = 128; off > 0; off >>= 1) {
        if (t < off) red[t] += red[t + off];
        __syncthreads();
    }
    float mu = red[0] * (1.0f / 256.0f);
    __syncthreads();
    float dvt = acc2 - mu;
    red[t] = dvt * dvt;
    __syncthreads();
    for (int off = 128; off > 0; off >>= 1) {
        if (t < off) red[t] += red[t + off];
        __syncthreads();
    }
    float va = red[0] * (1.0f / 256.0f);
    out[(size_t)b * FEAT + t] = dvt / sqrtf(va + 1e-5f) * gamma[t] + beta[t];
}

// --------------------------------------------------------------------------------------
extern "C" void kernel_launch(void* const* d_in, const int* in_sizes, int n_in,
                              void* d_out, int out_size, void* d_ws, size_t ws_size,
                              hipStream_t stream) {
    const float* x     = (const float*)d_in[0];
    const float* W1    = (const float*)d_in[1];
    const float* b1    = (const float*)d_in[2];
    const float* W2    = (const float*)d_in[3];
    const float* b2    = (const float*)d_in[4];
    const float* gamma = (const float*)d_in[5];
    const float* beta  = (const float*)d_in[6];
    float* out = (float*)d_out;

    char* ws = (char*)d_ws;
    unsigned* counts = (unsigned*)ws;
    float* partials = (float*)(ws + 256);
    const size_t partialsBytes = (size_t)NIMG * NGRP * KSEG * 3 * sizeof(float);
    const size_t intermOff = (256 + partialsBytes + 255) & ~(size_t)255;
    __half2* interm = (__half2*)(ws + intermOff);
    const size_t perImg = (size_t)1024 * 512 * sizeof(__half2);

    long long avail = (long long)ws_size - (long long)intermOff;
    int chunk = (avail > 0) ? (int)(avail / (long long)perImg) : 0;
    if (chunk > NIMG) chunk = NIMG;
    if (chunk < 1) chunk = 1;

    hipMemsetAsync(counts, 0, KSEG * sizeof(unsigned), stream);
    k_counts<<<dim3(128), dim3(256), 0, stream>>>(counts);

    for (int img0 = 0; img0 < NIMG; img0 += chunk) {
        int n = NIMG - img0;
        if (n > chunk) n = chunk;
        k_rowfft<<<dim3(32, n), dim3(1024), 0, stream>>>(x, interm, img0);
        k_colfft<<<dim3(NGRP, n), dim3(512), 0, stream>>>(interm, partials, img0);
    }

    k_mlp<<<dim3(32), dim3(256), 0, stream>>>(partials, counts, W1, b1, W2, b2,
                                              gamma, beta, out);
}

// Round 11
// 399.670 us; speedup vs baseline: 1.1422x; 1.0813x over previous
//
#include <hip/hip_runtime.h>
#include <hip/hip_fp16.h>
#include <math.h>

#define HH    1024
#define WWID  1024
#define WR    513
#define NIMG  96
#define NGRP  65
#define KSEG  17
#define FEAT  256
#define FIN   144

#if defined(__has_builtin)
#if __has_builtin(__builtin_amdgcn_permlane32_swap)
#define PERM32 1
#endif
#endif
#ifndef PERM32
#define PERM32 0
#endif

__device__ __forceinline__ float2 cmul(float2 a, float2 b) {
    return make_float2(a.x * b.x - a.y * b.y, a.x * b.y + a.y * b.x);
}

// exact reference binning (16 compares + sqrt) — used by k_counts
__device__ __forceinline__ int radial_bin(int hf, int k) {
    const float maxr = 0.707106781186547524f;
    float v = (float)(hf < 512 ? hf : hf - 1024) * (1.0f / 1024.0f);
    float u = (float)k * (1.0f / 1024.0f);
    float rad = sqrtf(u * u + v * v);
    int bin = 0;
#pragma unroll
    for (int l = 1; l <= 16; ++l) {
        float lower = (maxr * (float)l) * 0.0625f;
        bin += (rad >= lower) ? 1 : 0;
    }
    return bin;
}

// fast bin with exact boundary adjust (validated r6-r10)
__device__ __forceinline__ int fast_bin(float rad) {
    int c = (int)(rad * 22.62741699796952f);
    if (c > 16) c = 16;
    if (c < 16 && rad >= (0.707106781186547524f * (float)(c + 1)) * 0.0625f) c++;
    else if (rad < (0.707106781186547524f * (float)c) * 0.0625f) c--;
    return c;
}

__device__ constexpr int BR4[16] = {0,8,4,12,2,10,6,14,1,9,5,13,3,11,7,15};

// ---- cross-lane exchange: guaranteed single-issue ds ops -----------------------------
template<int HALF>
__device__ __forceinline__ float sxl(float v, int addr32) {
    if constexpr (HALF == 32)
        return __int_as_float(__builtin_amdgcn_ds_bpermute(addr32, __float_as_int(v)));
    else
        return __int_as_float(__builtin_amdgcn_ds_swizzle(__float_as_int(v),
                                                          (HALF << 10) | 0x1F));
}

template<int HALF>
__device__ __forceinline__ void fftC_stage(float2 a[16], int l, float2 u, int addr32) {
    const bool up = (l & HALF) != 0;
    const float sgn = up ? -1.0f : 1.0f;
    const float twx = up ? -u.x : 1.0f;   // down lanes: identity twiddle
    const float twy = up ? -u.y : 0.0f;
#pragma unroll
    for (int r = 0; r < 16; ++r) {
        float ox = sxl<HALF>(a[r].x, addr32);
        float oy = sxl<HALF>(a[r].y, addr32);
        float sx = fmaf(sgn, a[r].x, ox);   // down: a+o, up: o-a
        float sy = fmaf(sgn, a[r].y, oy);
        a[r].x = fmaf(sx, twx, -(sy * twy));
        a[r].y = fmaf(sx, twy, sy * twx);
    }
}

// stages 16..1 (shared). u must be W_32^l on entry.
__device__ __forceinline__ void wave_fft_C_tail(float2 a[16], int l, float2 u) {
    fftC_stage<16>(a, l, u, 0); u = cmul(u, u);
    fftC_stage<8>(a, l, u, 0);  u = cmul(u, u);
    fftC_stage<4>(a, l, u, 0);  u = cmul(u, u);
    fftC_stage<2>(a, l, u, 0);  u = cmul(u, u);
    fftC_stage<1>(a, l, u, 0);
}

// standard 64-pt DIF across lanes (rowfft + fallback). natural in -> bitrev out.
// u must be W_64^l.  Output: lane p, reg r <-> element 16*bitrev6(p)+r.
__device__ __forceinline__ void wave_fft_C(float2 a[16], int l, float2 u) {
    const int addr32 = ((l ^ 32) << 2);
    fftC_stage<32>(a, l, u, addr32);
    u = cmul(u, u);
    wave_fft_C_tail(a, l, u);
}

#if PERM32
// 64-pt DIF with stage-32 done via permlane32_swap mixing (no LDS ops for stage 32).
// Pairs (r, r+8): after swap, pr0=[A.lo|B.lo], pr1=[A.hi|B.hi];
// S = pr0+pr1 (down halves), D = pr0-pr1, T = D * t, t = (l<32 ? u : -u) = W64^(l&31).
// Resulting slot->row mapping (b=bitrev6(l), b'=b^1, lo=l<32):
//   slot r<8  (S_r): h = lo ? 16b+r      : 16b'+8+r
//   slot r>=8 (T_q): h = lo ? 16b'+(r-8) : 16b+8+(r-8)   [q=r-8]
__device__ __forceinline__ void wave_fft_C_mix(float2 a[16], int l, float2 u) {
    const bool lo = (l < 32);
    const float2 t = lo ? u : make_float2(-u.x, -u.y);
#pragma unroll
    for (int r = 0; r < 8; ++r) {
        unsigned ax = __float_as_uint(a[r].x), bx = __float_as_uint(a[r + 8].x);
        auto px = __builtin_amdgcn_permlane32_swap(ax, bx, false, false);
        unsigned ay = __float_as_uint(a[r].y), by = __float_as_uint(a[r + 8].y);
        auto py = __builtin_amdgcn_permlane32_swap(ay, by, false, false);
        float l0x = __uint_as_float(px[0]), h0x = __uint_as_float(px[1]);
        float l0y = __uint_as_float(py[0]), h0y = __uint_as_float(py[1]);
        a[r]     = make_float2(l0x + h0x, l0y + h0y);          // S_r
        a[r + 8] = cmul(make_float2(l0x - h0x, l0y - h0y), t); // T_r
    }
    u = cmul(u, u);
    wave_fft_C_tail(a, l, u);
}
#endif

// 16-pt DIT over registers: input reg r = element BR4[r] (bitrev order), natural out.
__device__ __forceinline__ void fft16_regs(float2 a[16]) {
    constexpr float TW16C[8] = {1.f, 0.9238795325112867f, 0.7071067811865476f,
                                0.3826834323650898f, 0.f, -0.3826834323650898f,
                                -0.7071067811865476f, -0.9238795325112867f};
    constexpr float TW16S[8] = {0.f, -0.3826834323650898f, -0.7071067811865476f,
                                -0.9238795325112867f, -1.f, -0.9238795325112867f,
                                -0.7071067811865476f, -0.3826834323650898f};
#pragma unroll
    for (int m = 2; m <= 16; m <<= 1) {
        const int half = m >> 1;
        const int tstep = 16 / m;
#pragma unroll
        for (int bse = 0; bse < 16; bse += m) {
#pragma unroll
            for (int jj = 0; jj < 8; ++jj) {
                if (jj < half) {
                    float2 w = make_float2(TW16C[jj * tstep], TW16S[jj * tstep]);
                    float2 tv = cmul(a[bse + half + jj], w);
                    float2 u0 = a[bse + jj];
                    a[bse + jj]        = make_float2(u0.x + tv.x, u0.y + tv.y);
                    a[bse + half + jj] = make_float2(u0.x - tv.x, u0.y - tv.y);
                }
            }
        }
    }
}

// twiddle a[r] *= wb^{e_r}; wb from __cosf/__sinf (|ang|<=0.39 rad), two-level chain.
template<bool PERM>  // e_r = PERM ? BR4[r] : r
__device__ __forceinline__ void twiddle_regs(float2 a[16], float ang, float2* w16out) {
    float2 w1 = make_float2(__cosf(ang), __sinf(ang));
    float2 w2 = cmul(w1, w1);
    float2 w3 = cmul(w2, w1);
    float2 w4 = cmul(w2, w2);
    float2 w8 = cmul(w4, w4);
    float2 w12 = cmul(w8, w4);
#pragma unroll
    for (int r = 1; r < 16; ++r) {
        const int e = PERM ? BR4[r] : r;
        float2 p = a[r];
        const int hi = e >> 2, lo = e & 3;
        if (hi == 1) p = cmul(p, w4);
        else if (hi == 2) p = cmul(p, w8);
        else if (hi == 3) p = cmul(p, w12);
        if (lo == 1) p = cmul(p, w1);
        else if (lo == 2) p = cmul(p, w2);
        else if (lo == 3) p = cmul(p, w3);
        a[r] = p;
    }
    if (w16out) *w16out = cmul(w8, w8);
}

// ---------------- Kernel 1: row FFTs (r10 structure, unchanged) ----------------------
__global__ __launch_bounds__(1024) void k_rowfft(const float* __restrict__ x,
                                                 __half2* __restrict__ interm,
                                                 int img0) {
    __shared__ __half2 tile[1024][17];
    const int t = threadIdx.x;
    const int w = t >> 6;
    const int l = t & 63;
    const int blk = blockIdx.x;           // 0..31
    const int iy = blockIdx.y;
    const int img = img0 + iy;
    const int hA = ((w & 7) << 6) + 2 * blk + (w >> 3);
    const int hB = hA + 512;

    const float4* r1 = (const float4*)(x + ((size_t)img * HH + hA) * WWID) + 4 * l;
    const float4* r2 = (const float4*)(x + ((size_t)img * HH + hB) * WWID) + 4 * l;
    float4 f1[4], f2[4];
#pragma unroll
    for (int c = 0; c < 4; ++c) { f1[c] = r1[c]; f2[c] = r2[c]; }

    float2 a[16];
#pragma unroll
    for (int j = 0; j < 16; ++j) {
        float v1 = ((const float*)f1)[j];
        float v2 = ((const float*)f2)[j];
        a[BR4[j]] = make_float2(v1, v2);
    }

    float angL = (float)l * (-6.28318530717958647692f / 64.0f);
    wave_fft_C(a, l, make_float2(__cosf(angL), __sinf(angL)));

    const int b = (int)(__brev((unsigned)l) >> 26);
    float angB = (float)b * (-6.28318530717958647692f / 1024.0f);
    twiddle_regs<true>(a, angB, nullptr);
    fft16_regs(a);

#pragma unroll
    for (int r = 0; r < 16; ++r)
        tile[b + 64 * r][w] = __floats2half2_rn(a[r].x, a[r].y);
    __syncthreads();

    __half2* gout = interm + (size_t)iy * 1024 * 512 + blk * 16;
#pragma unroll
    for (int it = 0; it < 16; ++it) {
        int idx = t + it * 1024;
        int k = idx >> 4;
        int s = idx & 15;
        gout[(size_t)k * 512 + s] = tile[k][s];
    }
}

// ------------- Kernel 2: column FFTs — permlane stage-32, remapped stats -------------
__global__ __launch_bounds__(512) void k_colfft(const __half2* __restrict__ interm,
                                                float* __restrict__ partials,
                                                int img0) {
    __shared__ float wsum[8][KSEG][8][2];      // [wave][bin][slot][s1,s2]
    __shared__ unsigned wmax[8][KSEG][8];
    const int t = threadIdx.x;
    const int g = blockIdx.x;
    const int iy = blockIdx.y;
    const int img = img0 + iy;
    const int wv = t >> 6;
    const int l = t & 63;
    const int k = g * 8 + wv;
    const int slot = l & 7;

    for (int i = t; i < 8 * 136; i += 512) {
        int w = i / 136;
        int rem = i - w * 136;
        int bb = rem >> 3, sl = rem & 7;
        wsum[w][bb][sl][0] = 0.f;
        wsum[w][bb][sl][1] = 0.f;
        wmax[w][bb][sl] = 0u;
    }
    __syncthreads();

    if (k <= 512) {   // wave-uniform
        const int kn = (1024 - k) & 1023;
        const uint4* ps = (const uint4*)(interm + ((size_t)iy * 1024 + k) * 512 + l * 8);
        const uint4* pn = (const uint4*)(interm + ((size_t)iy * 1024 + kn) * 512 + l * 8);
        union QU { uint4 q[2]; __half2 h[8]; } us, un;
        us.q[0] = ps[0]; us.q[1] = ps[1];
        un.q[0] = pn[0]; un.q[1] = pn[1];

        float2 a[16];
#pragma unroll
        for (int m = 0; m < 8; ++m) {
            float2 zs = __half22float2(us.h[m]);
            float2 zn = __half22float2(un.h[m]);
            a[BR4[m]]     = make_float2(0.5f * (zs.x + zn.x), 0.5f * (zs.y - zn.y));
            a[BR4[m + 8]] = make_float2(0.5f * (zs.y + zn.y), 0.5f * (zn.x - zs.x));
        }

        fft16_regs(a);
        float2 u16;
        float angB = (float)l * (-6.28318530717958647692f / 1024.0f);
        twiddle_regs<false>(a, angB, &u16);
#if PERM32
        wave_fft_C_mix(a, l, u16);
#else
        wave_fft_C(a, l, u16);
#endif

        // ---- stats: two 8-row runs per lane (span <= 24 rows -> at most 2 bins) ----
        const int b = (int)(__brev((unsigned)l) >> 26);
#if PERM32
        const int bX = b ^ 1;
        const bool lohalf = (l < 32);
        const int offS = lohalf ? 0 : 8;
        const int hS0 = 16 * (lohalf ? b : bX) + offS;   // rows for slots 0..7
        const int hT0 = 16 * (lohalf ? bX : b) + offS;   // rows for slots 8..15
        const int hmin = 16 * (b & ~1) + offS;
        const int hmax = 16 * (b | 1) + offS + 7;
#else
        const int hS0 = 16 * b;
        const int hT0 = 16 * b + 8;
        const int hmin = 16 * b;
        const int hmax = 16 * b + 15;
#endif
        const float uf = (float)k * (1.0f / 1024.0f);
        const float uu = uf * uf;
        const float vbS = (float)(hS0 < 512 ? hS0 : hS0 - 1024);
        const float vbT = (float)(hT0 < 512 ? hT0 : hT0 - 1024);
        float vmn = (float)(hmin < 512 ? hmin : hmin - 1024) * (1.0f / 1024.0f);
        float vmx = (float)(hmax < 512 ? hmax : hmax - 1024) * (1.0f / 1024.0f);
        int binF = fast_bin(sqrtf(fmaf(vmn, vmn, uu)));
        int binL = fast_bin(sqrtf(fmaf(vmx, vmx, uu)));
        const int bHi = (binF > binL) ? binF : binL;
        const float Lmid = (0.707106781186547524f * (float)bHi) * 0.0625f;
        const float Lmid2 = Lmid * Lmid;

        // totals + B-side; A-side derived (sA = sT - sB)
        float sT1 = 0.f, sT2 = 0.f, mA = 0.f;
        float sB1 = 0.f, sB2 = 0.f, mB = 0.f;
#pragma unroll
        for (int r = 0; r < 16; ++r) {
            float vf = (r < 8 ? (vbS + (float)r) : (vbT + (float)(r - 8)))
                       * (1.0f / 1024.0f);
            float s = fmaf(vf, vf, uu);                    // exact rad^2
            float2 z = a[r];
            float p2 = fmaf(z.x, z.x, z.y * z.y);
            float m = sqrtf(p2);
            bool c = (s >= Lmid2);                         // row in bin bHi
            sT1 += m;
            sT2 += p2;
            mA = fmaxf(mA, c ? m : 0.f);
            sB1 += c ? 0.f : m;
            sB2 += c ? 0.f : p2;
            mB = fmaxf(mB, c ? 0.f : m);
        }
        const float c1 = 1.0f / 1024.0f;
        const float c2 = 1.0f / 1048576.0f;
        float sA1 = sT1 - sB1;
        float sA2 = sT2 - sB2;

        atomicAdd(&wsum[wv][bHi][slot][0], sA1 * c1);
        atomicAdd(&wsum[wv][bHi][slot][1], sA2 * c2);
        atomicMax(&wmax[wv][bHi][slot], __float_as_uint(mA * c1));
        if (bHi > 0) {
            atomicAdd(&wsum[wv][bHi - 1][slot][0], sB1 * c1);
            atomicAdd(&wsum[wv][bHi - 1][slot][1], sB2 * c2);
            atomicMax(&wmax[wv][bHi - 1][slot], __float_as_uint(mB * c1));
        }
    }
    __syncthreads();

    if (t < KSEG) {
        float aS = 0.f, bS = 0.f, cM = 0.f;
#pragma unroll
        for (int w = 0; w < 8; ++w)
#pragma unroll
            for (int sl = 0; sl < 8; ++sl) {
                aS += wsum[w][t][sl][0];
                bS += wsum[w][t][sl][1];
                cM = fmaxf(cM, __uint_as_float(wmax[w][t][sl]));
            }
        float* dstp = partials + ((size_t)img * NGRP + g) * (KSEG * 3) + t * 3;
        dstp[0] = aS; dstp[1] = bS; dstp[2] = cM;
    }
}

// ---------------- counts (exact reference binning, no int division) ------------------
__global__ __launch_bounds__(256) void k_counts(unsigned* __restrict__ counts) {
    int cnt[KSEG];
#pragma unroll
    for (int l = 0; l < KSEG; ++l) cnt[l] = 0;
    const int tid = blockIdx.x * 256 + threadIdx.x;
    const int stride = gridDim.x * 256;
    for (int i = tid; i < 1024 * 512; i += stride) {
        int h = i >> 9;
        int k = i & 511;
        int bin = radial_bin(h, k);
#pragma unroll
        for (int l = 0; l < KSEG; ++l) cnt[l] += (bin == l) ? 1 : 0;
    }
    for (int j = tid; j < 1024; j += stride) {   // k = 512 column
        int bin = radial_bin(j, 512);
#pragma unroll
        for (int l = 0; l < KSEG; ++l) cnt[l] += (bin == l) ? 1 : 0;
    }
    const int lane = threadIdx.x & 63;
#pragma unroll
    for (int l = 0; l < KSEG; ++l) {
        int c = cnt[l];
        for (int off = 32; off > 0; off >>= 1) c += __shfl_xor(c, off);
        if (lane == 0 && c > 0) atomicAdd(&counts[l], (unsigned)c);
    }
}

// ---------------- Kernel 3: finalize stats + MLP + LayerNorm -------------------------
__global__ __launch_bounds__(256) void k_mlp(const float* __restrict__ partials,
                                             const unsigned* __restrict__ counts,
                                             const float* __restrict__ W1,
                                             const float* __restrict__ b1,
                                             const float* __restrict__ W2,
                                             const float* __restrict__ b2,
                                             const float* __restrict__ gamma,
                                             const float* __restrict__ beta,
                                             float* __restrict__ out) {
    __shared__ float feat[FIN];
    __shared__ float h1s[FEAT];
    __shared__ float red[FEAT];
    const int b = blockIdx.x;
    const int t = threadIdx.x;
    if (t < 48) {
        int c = t / 16;
        int bin = t % 16;
        const float* p = partials + ((size_t)(b * 3 + c) * NGRP) * (KSEG * 3) + bin * 3;
        float s1 = 0.f, s2 = 0.f, mxv = 0.f;
        for (int gg = 0; gg < NGRP; ++gg) {
            s1 += p[gg * (KSEG * 3) + 0];
            s2 += p[gg * (KSEG * 3) + 1];
            mxv = fmaxf(mxv, p[gg * (KSEG * 3) + 2]);
        }
        float cntf = (float)counts[bin];
        float denom = cntf + 1e-8f;
        float mean = s1 / denom;
        float var = (s2 - 2.0f * mean * s1 + cntf * mean * mean) / denom;
        var = fmaxf(var, 0.0f);
        float sd = sqrtf(var);
        mxv = fmaxf(mxv, 0.0f);
        feat[bin * 9 + 0 + c] = mean;
        feat[bin * 9 + 3 + c] = mxv;
        feat[bin * 9 + 6 + c] = sd;
    }
    __syncthreads();

    float acc = b1[t];
    for (int i = 0; i < FIN; ++i) acc += feat[i] * W1[i * FEAT + t];
    acc = (acc >= 0.0f) ? acc : 0.2f * acc;
    h1s[t] = acc;
    __syncthreads();

    float acc2 = b2[t];
    for (int i = 0; i < FEAT; ++i) acc2 += h1s[i] * W2[i * FEAT + t];

    red[t] = acc2;
    __syncthreads();
    for (int off = 128; off > 0; off >>= 1) {
        if (t < off) red[t] += red[t + off];
        __syncthreads();
    }
    float mu = red[0] * (1.0f / 256.0f);
    __syncthreads();
    float dvt = acc2 - mu;
    red[t] = dvt * dvt;
    __syncthreads();
    for (int off = 128; off > 0; off >>= 1) {
        if (t < off) red[t] += red[t + off];
        __syncthreads();
    }
    float va = red[0] * (1.0f / 256.0f);
    out[(size_t)b * FEAT + t] = dvt / sqrtf(va + 1e-5f) * gamma[t] + beta[t];
}

// --------------------------------------------------------------------------------------
extern "C" void kernel_launch(void* const* d_in, const int* in_sizes, int n_in,
                              void* d_out, int out_size, void* d_ws, size_t ws_size,
                              hipStream_t stream) {
    const float* x     = (const float*)d_in[0];
    const float* W1    = (const float*)d_in[1];
    const float* b1    = (const float*)d_in[2];
    const float* W2    = (const float*)d_in[3];
    const float* b2    = (const float*)d_in[4];
    const float* gamma = (const float*)d_in[5];
    const float* beta  = (const float*)d_in[6];
    float* out = (float*)d_out;

    char* ws = (char*)d_ws;
    unsigned* counts = (unsigned*)ws;
    float* partials = (float*)(ws + 256);
    const size_t partialsBytes = (size_t)NIMG * NGRP * KSEG * 3 * sizeof(float);
    const size_t intermOff = (256 + partialsBytes + 255) & ~(size_t)255;
    __half2* interm = (__half2*)(ws + intermOff);
    const size_t perImg = (size_t)1024 * 512 * sizeof(__half2);

    long long avail = (long long)ws_size - (long long)intermOff;
    int chunk = (avail > 0) ? (int)(avail / (long long)perImg) : 0;
    if (chunk > NIMG) chunk = NIMG;
    if (chunk < 1) chunk = 1;

    hipMemsetAsync(counts, 0, KSEG * sizeof(unsigned), stream);
    k_counts<<<dim3(128), dim3(256), 0, stream>>>(counts);

    for (int img0 = 0; img0 < NIMG; img0 += chunk) {
        int n = NIMG - img0;
        if (n > chunk) n = chunk;
        k_rowfft<<<dim3(32, n), dim3(1024), 0, stream>>>(x, interm, img0);
        k_colfft<<<dim3(NGRP, n), dim3(512), 0, stream>>>(interm, partials, img0);
    }

    k_mlp<<<dim3(32), dim3(256), 0, stream>>>(partials, counts, W1, b1, W2, b2,
                                              gamma, beta, out);
}

// Round 12
// 390.850 us; speedup vs baseline: 1.1680x; 1.0226x over previous
//
#include <hip/hip_runtime.h>
#include <hip/hip_fp16.h>
#include <math.h>

#define HH    1024
#define WWID  1024
#define WR    513
#define NIMG  96
#define NGRP  65
#define KSEG  17
#define FEAT  256
#define FIN   144

#if defined(__has_builtin)
#if __has_builtin(__builtin_amdgcn_permlane32_swap)
#define PERM32 1
#endif
#endif
#ifndef PERM32
#define PERM32 0
#endif

__device__ __forceinline__ float2 cmul(float2 a, float2 b) {
    return make_float2(a.x * b.x - a.y * b.y, a.x * b.y + a.y * b.x);
}

// exact reference binning (16 compares + sqrt) — used by k_counts
__device__ __forceinline__ int radial_bin(int hf, int k) {
    const float maxr = 0.707106781186547524f;
    float v = (float)(hf < 512 ? hf : hf - 1024) * (1.0f / 1024.0f);
    float u = (float)k * (1.0f / 1024.0f);
    float rad = sqrtf(u * u + v * v);
    int bin = 0;
#pragma unroll
    for (int l = 1; l <= 16; ++l) {
        float lower = (maxr * (float)l) * 0.0625f;
        bin += (rad >= lower) ? 1 : 0;
    }
    return bin;
}

// fast bin with exact boundary adjust (validated r6-r11)
__device__ __forceinline__ int fast_bin(float rad) {
    int c = (int)(rad * 22.62741699796952f);
    if (c > 16) c = 16;
    if (c < 16 && rad >= (0.707106781186547524f * (float)(c + 1)) * 0.0625f) c++;
    else if (rad < (0.707106781186547524f * (float)c) * 0.0625f) c--;
    return c;
}

__device__ constexpr int BR4[16] = {0,8,4,12,2,10,6,14,1,9,5,13,3,11,7,15};

// ---- cross-lane exchange: DPP where an exact pattern exists, ds ops otherwise -------
// xor1 = quad_perm[1,0,3,2] (0xB1); xor2 = quad_perm[2,3,0,1] (0x4E);
// xor8 = row_ror:8 (0x128), since (l+8) mod 16 == l^8.  All bit-exact moves.
template<int HALF>
__device__ __forceinline__ float sxl(float v, int addr32) {
    int vi = __float_as_int(v);
    if constexpr (HALF == 32)
        return __int_as_float(__builtin_amdgcn_ds_bpermute(addr32, vi));
    else if constexpr (HALF == 8)
        return __int_as_float(__builtin_amdgcn_update_dpp(vi, vi, 0x128, 0xF, 0xF, true));
    else if constexpr (HALF == 2)
        return __int_as_float(__builtin_amdgcn_update_dpp(vi, vi, 0x4E, 0xF, 0xF, true));
    else if constexpr (HALF == 1)
        return __int_as_float(__builtin_amdgcn_update_dpp(vi, vi, 0xB1, 0xF, 0xF, true));
    else
        return __int_as_float(__builtin_amdgcn_ds_swizzle(vi, (HALF << 10) | 0x1F));
}

template<int HALF>
__device__ __forceinline__ void fftC_stage(float2 a[16], int l, float2 u, int addr32) {
    const bool up = (l & HALF) != 0;
    const float sgn = up ? -1.0f : 1.0f;
    const float twx = up ? -u.x : 1.0f;   // down lanes: identity twiddle
    const float twy = up ? -u.y : 0.0f;
#pragma unroll
    for (int r = 0; r < 16; ++r) {
        float ox = sxl<HALF>(a[r].x, addr32);
        float oy = sxl<HALF>(a[r].y, addr32);
        float sx = fmaf(sgn, a[r].x, ox);   // down: a+o, up: o-a
        float sy = fmaf(sgn, a[r].y, oy);
        a[r].x = fmaf(sx, twx, -(sy * twy));
        a[r].y = fmaf(sx, twy, sy * twx);
    }
}

// stages 16..1 (shared). u must be W_32^l on entry.
__device__ __forceinline__ void wave_fft_C_tail(float2 a[16], int l, float2 u) {
    fftC_stage<16>(a, l, u, 0); u = cmul(u, u);
    fftC_stage<8>(a, l, u, 0);  u = cmul(u, u);
    fftC_stage<4>(a, l, u, 0);  u = cmul(u, u);
    fftC_stage<2>(a, l, u, 0);  u = cmul(u, u);
    fftC_stage<1>(a, l, u, 0);
}

// standard 64-pt DIF across lanes (rowfft). natural in -> bitrev out.
// u must be W_64^l.  Output: lane p, reg r <-> element 16*bitrev6(p)+r.
__device__ __forceinline__ void wave_fft_C(float2 a[16], int l, float2 u) {
    const int addr32 = ((l ^ 32) << 2);
    fftC_stage<32>(a, l, u, addr32);
    u = cmul(u, u);
    wave_fft_C_tail(a, l, u);
}

#if PERM32
// 64-pt DIF with stage-32 via permlane32_swap mixing (verified r11).
// slot r<8  (S_r): h = lo ? 16b+r      : 16b'+8+r
// slot r>=8 (T_q): h = lo ? 16b'+(r-8) : 16b+8+(r-8)   [q=r-8, b'=b^1]
__device__ __forceinline__ void wave_fft_C_mix(float2 a[16], int l, float2 u) {
    const bool lo = (l < 32);
    const float2 t = lo ? u : make_float2(-u.x, -u.y);
#pragma unroll
    for (int r = 0; r < 8; ++r) {
        unsigned ax = __float_as_uint(a[r].x), bx = __float_as_uint(a[r + 8].x);
        auto px = __builtin_amdgcn_permlane32_swap(ax, bx, false, false);
        unsigned ay = __float_as_uint(a[r].y), by = __float_as_uint(a[r + 8].y);
        auto py = __builtin_amdgcn_permlane32_swap(ay, by, false, false);
        float l0x = __uint_as_float(px[0]), h0x = __uint_as_float(px[1]);
        float l0y = __uint_as_float(py[0]), h0y = __uint_as_float(py[1]);
        a[r]     = make_float2(l0x + h0x, l0y + h0y);          // S_r
        a[r + 8] = cmul(make_float2(l0x - h0x, l0y - h0y), t); // T_r
    }
    u = cmul(u, u);
    wave_fft_C_tail(a, l, u);
}
#endif

// 16-pt DIT over registers: input reg r = element BR4[r] (bitrev order), natural out.
__device__ __forceinline__ void fft16_regs(float2 a[16]) {
    constexpr float TW16C[8] = {1.f, 0.9238795325112867f, 0.7071067811865476f,
                                0.3826834323650898f, 0.f, -0.3826834323650898f,
                                -0.7071067811865476f, -0.9238795325112867f};
    constexpr float TW16S[8] = {0.f, -0.3826834323650898f, -0.7071067811865476f,
                                -0.9238795325112867f, -1.f, -0.9238795325112867f,
                                -0.7071067811865476f, -0.3826834323650898f};
#pragma unroll
    for (int m = 2; m <= 16; m <<= 1) {
        const int half = m >> 1;
        const int tstep = 16 / m;
#pragma unroll
        for (int bse = 0; bse < 16; bse += m) {
#pragma unroll
            for (int jj = 0; jj < 8; ++jj) {
                if (jj < half) {
                    float2 w = make_float2(TW16C[jj * tstep], TW16S[jj * tstep]);
                    float2 tv = cmul(a[bse + half + jj], w);
                    float2 u0 = a[bse + jj];
                    a[bse + jj]        = make_float2(u0.x + tv.x, u0.y + tv.y);
                    a[bse + half + jj] = make_float2(u0.x - tv.x, u0.y - tv.y);
                }
            }
        }
    }
}

// twiddle a[r] *= wb^{e_r}; wb from __cosf/__sinf (|ang|<=0.39 rad), two-level chain.
template<bool PERM>  // e_r = PERM ? BR4[r] : r
__device__ __forceinline__ void twiddle_regs(float2 a[16], float ang, float2* w16out) {
    float2 w1 = make_float2(__cosf(ang), __sinf(ang));
    float2 w2 = cmul(w1, w1);
    float2 w3 = cmul(w2, w1);
    float2 w4 = cmul(w2, w2);
    float2 w8 = cmul(w4, w4);
    float2 w12 = cmul(w8, w4);
#pragma unroll
    for (int r = 1; r < 16; ++r) {
        const int e = PERM ? BR4[r] : r;
        float2 p = a[r];
        const int hi = e >> 2, lo = e & 3;
        if (hi == 1) p = cmul(p, w4);
        else if (hi == 2) p = cmul(p, w8);
        else if (hi == 3) p = cmul(p, w12);
        if (lo == 1) p = cmul(p, w1);
        else if (lo == 2) p = cmul(p, w2);
        else if (lo == 3) p = cmul(p, w3);
        a[r] = p;
    }
    if (w16out) *w16out = cmul(w8, w8);
}

// ---------------- Kernel 1: row FFTs (r10/r11 structure) -----------------------------
__global__ __launch_bounds__(1024) void k_rowfft(const float* __restrict__ x,
                                                 __half2* __restrict__ interm,
                                                 int img0) {
    __shared__ __half2 tile[1024][17];
    const int t = threadIdx.x;
    const int w = t >> 6;
    const int l = t & 63;
    const int blk = blockIdx.x;           // 0..31
    const int iy = blockIdx.y;
    const int img = img0 + iy;
    const int hA = ((w & 7) << 6) + 2 * blk + (w >> 3);
    const int hB = hA + 512;

    const float4* r1 = (const float4*)(x + ((size_t)img * HH + hA) * WWID) + 4 * l;
    const float4* r2 = (const float4*)(x + ((size_t)img * HH + hB) * WWID) + 4 * l;
    float4 f1[4], f2[4];
#pragma unroll
    for (int c = 0; c < 4; ++c) { f1[c] = r1[c]; f2[c] = r2[c]; }

    float2 a[16];
#pragma unroll
    for (int j = 0; j < 16; ++j) {
        float v1 = ((const float*)f1)[j];
        float v2 = ((const float*)f2)[j];
        a[BR4[j]] = make_float2(v1, v2);
    }

    float angL = (float)l * (-6.28318530717958647692f / 64.0f);
    wave_fft_C(a, l, make_float2(__cosf(angL), __sinf(angL)));

    const int b = (int)(__brev((unsigned)l) >> 26);
    float angB = (float)b * (-6.28318530717958647692f / 1024.0f);
    twiddle_regs<true>(a, angB, nullptr);
    fft16_regs(a);

#pragma unroll
    for (int r = 0; r < 16; ++r)
        tile[b + 64 * r][w] = __floats2half2_rn(a[r].x, a[r].y);
    __syncthreads();

    __half2* gout = interm + (size_t)iy * 1024 * 512 + blk * 16;
#pragma unroll
    for (int it = 0; it < 16; ++it) {
        int idx = t + it * 1024;
        int k = idx >> 4;
        int s = idx & 15;
        gout[(size_t)k * 512 + s] = tile[k][s];
    }
}

// ------------- Kernel 2: column FFTs — permlane stage-32, DPP tail, folded 0.5 -------
__global__ __launch_bounds__(512) void k_colfft(const __half2* __restrict__ interm,
                                                float* __restrict__ partials,
                                                int img0) {
    __shared__ float wsum[8][KSEG][8][2];      // [wave][bin][slot][s1,s2]
    __shared__ unsigned wmax[8][KSEG][8];
    const int t = threadIdx.x;
    const int g = blockIdx.x;
    const int iy = blockIdx.y;
    const int img = img0 + iy;
    const int wv = t >> 6;
    const int l = t & 63;
    const int k = g * 8 + wv;
    const int slot = l & 7;

    for (int i = t; i < 8 * 136; i += 512) {
        int w = i / 136;
        int rem = i - w * 136;
        int bb = rem >> 3, sl = rem & 7;
        wsum[w][bb][sl][0] = 0.f;
        wsum[w][bb][sl][1] = 0.f;
        wmax[w][bb][sl] = 0u;
    }
    __syncthreads();

    if (k <= 512) {   // wave-uniform
        const int kn = (1024 - k) & 1023;
        const uint4* ps = (const uint4*)(interm + ((size_t)iy * 1024 + k) * 512 + l * 8);
        const uint4* pn = (const uint4*)(interm + ((size_t)iy * 1024 + kn) * 512 + l * 8);
        union QU { uint4 q[2]; __half2 h[8]; } us, un;
        us.q[0] = ps[0]; us.q[1] = ps[1];
        un.q[0] = pn[0]; un.q[1] = pn[1];

        // unpack WITHOUT the 0.5 factors (folded into c1/c2 below; FFT is linear)
        float2 a[16];
#pragma unroll
        for (int m = 0; m < 8; ++m) {
            float2 zs = __half22float2(us.h[m]);
            float2 zn = __half22float2(un.h[m]);
            a[BR4[m]]     = make_float2(zs.x + zn.x, zs.y - zn.y);
            a[BR4[m + 8]] = make_float2(zs.y + zn.y, zn.x - zs.x);
        }

        fft16_regs(a);
        float2 u16;
        float angB = (float)l * (-6.28318530717958647692f / 1024.0f);
        twiddle_regs<false>(a, angB, &u16);
#if PERM32
        wave_fft_C_mix(a, l, u16);
#else
        wave_fft_C(a, l, u16);
#endif

        // ---- stats: two 8-row runs per lane (span <= 24 rows -> at most 2 bins) ----
        const int b = (int)(__brev((unsigned)l) >> 26);
#if PERM32
        const int bX = b ^ 1;
        const bool lohalf = (l < 32);
        const int offS = lohalf ? 0 : 8;
        const int hS0 = 16 * (lohalf ? b : bX) + offS;   // rows for slots 0..7
        const int hT0 = 16 * (lohalf ? bX : b) + offS;   // rows for slots 8..15
        const int hmin = 16 * (b & ~1) + offS;
        const int hmax = 16 * (b | 1) + offS + 7;
#else
        const int hS0 = 16 * b;
        const int hT0 = 16 * b + 8;
        const int hmin = 16 * b;
        const int hmax = 16 * b + 15;
#endif
        const float uf = (float)k * (1.0f / 1024.0f);
        const float uu = uf * uf;
        const float vbS = (float)(hS0 < 512 ? hS0 : hS0 - 1024);
        const float vbT = (float)(hT0 < 512 ? hT0 : hT0 - 1024);
        float vmn = (float)(hmin < 512 ? hmin : hmin - 1024) * (1.0f / 1024.0f);
        float vmx = (float)(hmax < 512 ? hmax : hmax - 1024) * (1.0f / 1024.0f);
        int binF = fast_bin(sqrtf(fmaf(vmn, vmn, uu)));
        int binL = fast_bin(sqrtf(fmaf(vmx, vmx, uu)));
        const int bHi = (binF > binL) ? binF : binL;
        const float Lmid = (0.707106781186547524f * (float)bHi) * 0.0625f;
        const float Lmid2 = Lmid * Lmid;

        // totals + B-side; A-side derived (sA = sT - sB)
        float sT1 = 0.f, sT2 = 0.f, mA = 0.f;
        float sB1 = 0.f, sB2 = 0.f, mB = 0.f;
#pragma unroll
        for (int r = 0; r < 16; ++r) {
            float vf = (r < 8 ? (vbS + (float)r) : (vbT + (float)(r - 8)))
                       * (1.0f / 1024.0f);
            float s = fmaf(vf, vf, uu);                    // exact rad^2
            float2 z = a[r];
            float p2 = fmaf(z.x, z.x, z.y * z.y);
            float m = sqrtf(p2);
            bool c = (s >= Lmid2);                         // row in bin bHi
            sT1 += m;
            sT2 += p2;
            mA = fmaxf(mA, c ? m : 0.f);
            sB1 += c ? 0.f : m;
            sB2 += c ? 0.f : p2;
            mB = fmaxf(mB, c ? 0.f : m);
        }
        // values are 2x reference (unpack 0.5 folded): c1 = 1/(2*1024), c2 = 1/(4*1024^2)
        const float c1 = 1.0f / 2048.0f;
        const float c2 = 1.0f / 4194304.0f;
        float sA1 = sT1 - sB1;
        float sA2 = sT2 - sB2;

        atomicAdd(&wsum[wv][bHi][slot][0], sA1 * c1);
        atomicAdd(&wsum[wv][bHi][slot][1], sA2 * c2);
        atomicMax(&wmax[wv][bHi][slot], __float_as_uint(mA * c1));
        if (bHi > 0) {
            atomicAdd(&wsum[wv][bHi - 1][slot][0], sB1 * c1);
            atomicAdd(&wsum[wv][bHi - 1][slot][1], sB2 * c2);
            atomicMax(&wmax[wv][bHi - 1][slot], __float_as_uint(mB * c1));
        }
    }
    __syncthreads();

    if (t < KSEG) {
        float aS = 0.f, bS = 0.f, cM = 0.f;
#pragma unroll
        for (int w = 0; w < 8; ++w)
#pragma unroll
            for (int sl = 0; sl < 8; ++sl) {
                aS += wsum[w][t][sl][0];
                bS += wsum[w][t][sl][1];
                cM = fmaxf(cM, __uint_as_float(wmax[w][t][sl]));
            }
        float* dstp = partials + ((size_t)img * NGRP + g) * (KSEG * 3) + t * 3;
        dstp[0] = aS; dstp[1] = bS; dstp[2] = cM;
    }
}

// ---------------- counts (exact reference binning, no int division) ------------------
__global__ __launch_bounds__(256) void k_counts(unsigned* __restrict__ counts) {
    int cnt[KSEG];
#pragma unroll
    for (int l = 0; l < KSEG; ++l) cnt[l] = 0;
    const int tid = blockIdx.x * 256 + threadIdx.x;
    const int stride = gridDim.x * 256;
    for (int i = tid; i < 1024 * 512; i += stride) {
        int h = i >> 9;
        int k = i & 511;
        int bin = radial_bin(h, k);
#pragma unroll
        for (int l = 0; l < KSEG; ++l) cnt[l] += (bin == l) ? 1 : 0;
    }
    for (int j = tid; j < 1024; j += stride) {   // k = 512 column
        int bin = radial_bin(j, 512);
#pragma unroll
        for (int l = 0; l < KSEG; ++l) cnt[l] += (bin == l) ? 1 : 0;
    }
    const int lane = threadIdx.x & 63;
#pragma unroll
    for (int l = 0; l < KSEG; ++l) {
        int c = cnt[l];
        for (int off = 32; off > 0; off >>= 1) c += __shfl_xor(c, off);
        if (lane == 0 && c > 0) atomicAdd(&counts[l], (unsigned)c);
    }
}

// ---------------- Kernel 3: finalize stats + MLP + LayerNorm -------------------------
__global__ __launch_bounds__(256) void k_mlp(const float* __restrict__ partials,
                                             const unsigned* __restrict__ counts,
                                             const float* __restrict__ W1,
                                             const float* __restrict__ b1,
                                             const float* __restrict__ W2,
                                             const float* __restrict__ b2,
                                             const float* __restrict__ gamma,
                                             const float* __restrict__ beta,
                                             float* __restrict__ out) {
    __shared__ float feat[FIN];
    __shared__ float h1s[FEAT];
    __shared__ float red[FEAT];
    const int b = blockIdx.x;
    const int t = threadIdx.x;
    if (t < 48) {
        int c = t / 16;
        int bin = t % 16;
        const float* p = partials + ((size_t)(b * 3 + c) * NGRP) * (KSEG * 3) + bin * 3;
        float s1 = 0.f, s2 = 0.f, mxv = 0.f;
        for (int gg = 0; gg < NGRP; ++gg) {
            s1 += p[gg * (KSEG * 3) + 0];
            s2 += p[gg * (KSEG * 3) + 1];
            mxv = fmaxf(mxv, p[gg * (KSEG * 3) + 2]);
        }
        float cntf = (float)counts[bin];
        float denom = cntf + 1e-8f;
        float mean = s1 / denom;
        float var = (s2 - 2.0f * mean * s1 + cntf * mean * mean) / denom;
        var = fmaxf(var, 0.0f);
        float sd = sqrtf(var);
        mxv = fmaxf(mxv, 0.0f);
        feat[bin * 9 + 0 + c] = mean;
        feat[bin * 9 + 3 + c] = mxv;
        feat[bin * 9 + 6 + c] = sd;
    }
    __syncthreads();

    float acc = b1[t];
    for (int i = 0; i < FIN; ++i) acc += feat[i] * W1[i * FEAT + t];
    acc = (acc >= 0.0f) ? acc : 0.2f * acc;
    h1s[t] = acc;
    __syncthreads();

    float acc2 = b2[t];
    for (int i = 0; i < FEAT; ++i) acc2 += h1s[i] * W2[i * FEAT + t];

    red[t] = acc2;
    __syncthreads();
    for (int off = 128; off > 0; off >>= 1) {
        if (t < off) red[t] += red[t + off];
        __syncthreads();
    }
    float mu = red[0] * (1.0f / 256.0f);
    __syncthreads();
    float dvt = acc2 - mu;
    red[t] = dvt * dvt;
    __syncthreads();
    for (int off = 128; off > 0; off >>= 1) {
        if (t < off) red[t] += red[t + off];
        __syncthreads();
    }
    float va = red[0] * (1.0f / 256.0f);
    out[(size_t)b * FEAT + t] = dvt / sqrtf(va + 1e-5f) * gamma[t] + beta[t];
}

// --------------------------------------------------------------------------------------
extern "C" void kernel_launch(void* const* d_in, const int* in_sizes, int n_in,
                              void* d_out, int out_size, void* d_ws, size_t ws_size,
                              hipStream_t stream) {
    const float* x     = (const float*)d_in[0];
    const float* W1    = (const float*)d_in[1];
    const float* b1    = (const float*)d_in[2];
    const float* W2    = (const float*)d_in[3];
    const float* b2    = (const float*)d_in[4];
    const float* gamma = (const float*)d_in[5];
    const float* beta  = (const float*)d_in[6];
    float* out = (float*)d_out;

    char* ws = (char*)d_ws;
    unsigned* counts = (unsigned*)ws;
    float* partials = (float*)(ws + 256);
    const size_t partialsBytes = (size_t)NIMG * NGRP * KSEG * 3 * sizeof(float);
    const size_t intermOff = (256 + partialsBytes + 255) & ~(size_t)255;
    __half2* interm = (__half2*)(ws + intermOff);
    const size_t perImg = (size_t)1024 * 512 * sizeof(__half2);

    long long avail = (long long)ws_size - (long long)intermOff;
    int chunk = (avail > 0) ? (int)(avail / (long long)perImg) : 0;
    if (chunk > NIMG) chunk = NIMG;
    if (chunk < 1) chunk = 1;

    hipMemsetAsync(counts, 0, KSEG * sizeof(unsigned), stream);
    k_counts<<<dim3(128), dim3(256), 0, stream>>>(counts);

    for (int img0 = 0; img0 < NIMG; img0 += chunk) {
        int n = NIMG - img0;
        if (n > chunk) n = chunk;
        k_rowfft<<<dim3(32, n), dim3(1024), 0, stream>>>(x, interm, img0);
        k_colfft<<<dim3(NGRP, n), dim3(512), 0, stream>>>(interm, partials, img0);
    }

    k_mlp<<<dim3(32), dim3(256), 0, stream>>>(partials, counts, W1, b1, W2, b2,
                                              gamma, beta, out);
}